// Round 6
// baseline (3680.560 us; speedup 1.0000x reference)
//
#include <hip/hip_runtime.h>

#define NN 40000
#define EE 640000
#define GRID 1024
#define NCH 157   // ceil(NN/256)

typedef unsigned int uint;
typedef unsigned short ushort;
typedef __attribute__((ext_vector_type(8))) short short8;
typedef __attribute__((ext_vector_type(4))) float floatx4;

// ---- bf16 helpers (RNE) ----
__device__ inline ushort f2bf(float f) {
    uint u = __float_as_uint(f);
    return (ushort)((u + 0x7fffu + ((u >> 16) & 1u)) >> 16);
}
__device__ inline float bf_lo(uint u) { return __uint_as_float(u << 16); }
__device__ inline float bf_hi(uint u) { return __uint_as_float(u & 0xffff0000u); }

// ---- shared-memory union across phases ----
struct FinalSM { float pooled[16][128]; float z[16][64]; int cnt[16]; };
struct SM {
    union {
        int sc[256];          // scan phase
        int2 eds[4][64];      // agg phases (per-wave neighbor records)
        FinalSM f;            // final MLP phase (12.1 KB, max member)
    };
    int ws[4];
};

// ---- software grid barrier (all GRID blocks co-resident by construction) ----
// Per-block arrival slots (no contended atomics); block 0 collects and
// releases a generation flag. Agent-scope atomics + threadfence give
// cross-XCD visibility (per-XCD L2s are non-coherent).
__device__ inline void gridbar(int* __restrict__ slots, int* __restrict__ gen, int phase) {
    __syncthreads();
    __threadfence();
    if (blockIdx.x == 0) {
        if (threadIdx.x < 64) {
            for (int s = 1 + (int)threadIdx.x; s < GRID; s += 64) {
                int guard = 0;
                while (__hip_atomic_load(&slots[s], __ATOMIC_RELAXED, __HIP_MEMORY_SCOPE_AGENT) < phase) {
                    __builtin_amdgcn_s_sleep(2);
                    if (++guard > (1 << 24)) break;   // safety: never hard-hang
                }
            }
        }
        __syncthreads();
        if (threadIdx.x == 0)
            __hip_atomic_store(gen, phase, __ATOMIC_RELEASE, __HIP_MEMORY_SCOPE_AGENT);
    } else {
        if (threadIdx.x == 0) {
            __hip_atomic_store(&slots[blockIdx.x], phase, __ATOMIC_RELEASE, __HIP_MEMORY_SCOPE_AGENT);
            int guard = 0;
            while (__hip_atomic_load(gen, __ATOMIC_ACQUIRE, __HIP_MEMORY_SCOPE_AGENT) < phase) {
                __builtin_amdgcn_s_sleep(2);
                if (++guard > (1 << 26)) break;
            }
        }
    }
    __syncthreads();
    __threadfence();
}

// ---- MFMA 64-row tile: C[64,128](bf16) = A[64,128] @ Bpack ----
template <bool ABF16>
__device__ inline void mm_tile(const void* __restrict__ Av, const ushort* __restrict__ Bpack,
                               ushort* __restrict__ C, int tile, int wv, int lane) {
    int m = lane & 15, q = lane >> 4;
    int row = tile * 64 + wv * 16 + m;

    short8 afr[4];
    if (ABF16) {
        const ushort* A = (const ushort*)Av;
        const ushort* ap = A + (size_t)row * 128 + q * 8;
        #pragma unroll
        for (int k0 = 0; k0 < 4; ++k0) afr[k0] = *(const short8*)(ap + k0 * 32);
    } else {
        const float* A = (const float*)Av;
        const float* ap = A + (size_t)row * 128 + q * 8;
        #pragma unroll
        for (int k0 = 0; k0 < 4; ++k0) {
            float4 f0 = *(const float4*)(ap + k0 * 32);
            float4 f1 = *(const float4*)(ap + k0 * 32 + 4);
            short8 a;
            a[0] = (short)f2bf(f0.x); a[1] = (short)f2bf(f0.y);
            a[2] = (short)f2bf(f0.z); a[3] = (short)f2bf(f0.w);
            a[4] = (short)f2bf(f1.x); a[5] = (short)f2bf(f1.y);
            a[6] = (short)f2bf(f1.z); a[7] = (short)f2bf(f1.w);
            afr[k0] = a;
        }
    }

    floatx4 acc[8];
    #pragma unroll
    for (int nt = 0; nt < 8; ++nt) { floatx4 z = {0.f, 0.f, 0.f, 0.f}; acc[nt] = z; }

    #pragma unroll
    for (int nt = 0; nt < 8; ++nt) {
        #pragma unroll
        for (int k0 = 0; k0 < 4; ++k0) {
            short8 bfrag = *(const short8*)(Bpack + ((size_t)(k0 * 4 + q) * 128 + nt * 16 + m) * 8);
            acc[nt] = __builtin_amdgcn_mfma_f32_16x16x32_bf16(afr[k0], bfrag, acc[nt], 0, 0, 0);
        }
    }

    int orow_base = tile * 64 + wv * 16 + q * 4;
    #pragma unroll
    for (int nt = 0; nt < 8; ++nt) {
        #pragma unroll
        for (int r = 0; r < 4; ++r)
            C[(size_t)(orow_base + r) * 128 + nt * 16 + m] = f2bf(acc[nt][r]);
    }
}

// ---- GCN aggregation for one node (one wave), LDS-preloaded neighbor list ----
__device__ inline void agg_node(const ushort* __restrict__ hw, const float* __restrict__ dis,
                                const int* __restrict__ rowptr, const int2* __restrict__ edata,
                                const float* __restrict__ cvec, const float* __restrict__ bias,
                                ushort* __restrict__ outp, int i, int wv, int lane,
                                int2 (*eds)[64]) {
    int beg = rowptr[i], end = rowptr[i + 1];
    int deg = end - beg;
    int dmain = deg > 64 ? 64 : deg;
    const uint* __restrict__ hv = (const uint*)hw;

    int2 ed;
    if (lane < dmain) ed = edata[beg + lane];
    else { ed.x = i; ed.y = 0; }
    eds[wv][lane] = ed;

    float di = dis[i];
    float sii = di * di;
    uint su = hv[(size_t)i * 64 + lane];
    float a0 = sii * bf_lo(su);
    float a1 = sii * bf_hi(su);
    float sumnorm = sii;

    int dpad = (dmain + 7) & ~7;
    for (int j = 0; j < dpad; j += 8) {
        int2 e0 = eds[wv][j],     e1 = eds[wv][j + 1];
        int2 e2 = eds[wv][j + 2], e3 = eds[wv][j + 3];
        int2 e4 = eds[wv][j + 4], e5 = eds[wv][j + 5];
        int2 e6 = eds[wv][j + 6], e7 = eds[wv][j + 7];
        uint u0 = hv[(size_t)e0.x * 64 + lane];
        uint u1 = hv[(size_t)e1.x * 64 + lane];
        uint u2 = hv[(size_t)e2.x * 64 + lane];
        uint u3 = hv[(size_t)e3.x * 64 + lane];
        uint u4 = hv[(size_t)e4.x * 64 + lane];
        uint u5 = hv[(size_t)e5.x * 64 + lane];
        uint u6 = hv[(size_t)e6.x * 64 + lane];
        uint u7 = hv[(size_t)e7.x * 64 + lane];
        float n0 = __int_as_float(e0.y), n1 = __int_as_float(e1.y);
        float n2 = __int_as_float(e2.y), n3 = __int_as_float(e3.y);
        float n4 = __int_as_float(e4.y), n5 = __int_as_float(e5.y);
        float n6 = __int_as_float(e6.y), n7 = __int_as_float(e7.y);
        a0 = fmaf(n0, bf_lo(u0), a0); a1 = fmaf(n0, bf_hi(u0), a1);
        a0 = fmaf(n1, bf_lo(u1), a0); a1 = fmaf(n1, bf_hi(u1), a1);
        a0 = fmaf(n2, bf_lo(u2), a0); a1 = fmaf(n2, bf_hi(u2), a1);
        a0 = fmaf(n3, bf_lo(u3), a0); a1 = fmaf(n3, bf_hi(u3), a1);
        a0 = fmaf(n4, bf_lo(u4), a0); a1 = fmaf(n4, bf_hi(u4), a1);
        a0 = fmaf(n5, bf_lo(u5), a0); a1 = fmaf(n5, bf_hi(u5), a1);
        a0 = fmaf(n6, bf_lo(u6), a0); a1 = fmaf(n6, bf_hi(u6), a1);
        a0 = fmaf(n7, bf_lo(u7), a0); a1 = fmaf(n7, bf_hi(u7), a1);
        sumnorm += ((n0 + n1) + (n2 + n3)) + ((n4 + n5) + (n6 + n7));
    }
    for (int e = beg + 64; e < end; ++e) {   // rare deg>64 tail
        int2 et = edata[e];
        float n0 = __int_as_float(et.y);
        uint u0 = hv[(size_t)et.x * 64 + lane];
        a0 = fmaf(n0, bf_lo(u0), a0);
        a1 = fmaf(n0, bf_hi(u0), a1);
        sumnorm += n0;
    }

    float c0 = 0.f, c1 = 0.f;
    if (cvec) { c0 = cvec[2 * lane]; c1 = cvec[2 * lane + 1]; }
    float b0 = bias[2 * lane], b1 = bias[2 * lane + 1];
    float o0 = fmaxf(fmaf(sumnorm, c0, a0) + b0, 0.f);
    float o1 = fmaxf(fmaf(sumnorm, c1, a1) + b1, 0.f);
    uint o = (uint)f2bf(o0) | ((uint)f2bf(o1) << 16);
    ((uint*)outp)[(size_t)i * 64 + lane] = o;
}

__device__ inline int lower_bound_dev(const int* __restrict__ a, int n, int x) {
    int lo = 0, hi = n;
    while (lo < hi) { int m = (lo + hi) >> 1; if (a[m] < x) lo = m + 1; else hi = m; }
    return lo;
}

// ================= the mega-kernel =================
__global__ __launch_bounds__(256, 4) void mega(
    const float* __restrict__ x, const int* __restrict__ esrc, const int* __restrict__ edst,
    const int* __restrict__ batch,
    const float* __restrict__ W_in, const float* __restrict__ b_in,
    const float* __restrict__ W1, const float* __restrict__ b1,
    const float* __restrict__ W2, const float* __restrict__ b2,
    const float* __restrict__ Wf1, const float* __restrict__ bf1,
    const float* __restrict__ Wf2, const float* __restrict__ bf2,
    float* __restrict__ out,
    int* slots, int* gen, int* counts, int* bsum, int* rowptr, int* cursor,
    float* dis, int2* edata, float* pools, float* cvec,
    ushort* Bp1, ushort* Bp2, ushort* bufA, ushort* bufB) {

    __shared__ SM sm;
    int t = threadIdx.x, b = blockIdx.x;
    int lane = t & 63, wv = t >> 6;

    // ---- P0: zero counts/pools + weight prep ----
    if (b < NCH) {
        int idx = b * 256 + t;
        if (idx < NN) counts[idx] = 0;
    } else if (b == NCH) {
        #pragma unroll
        for (int j = 0; j < 8; ++j) pools[j * 256 + t] = 0.f;
    } else if (b >= 160 && b < 224) {
        int idx = (b - 160) * 256 + t;
        int k = idx >> 7, n = idx & 127;
        float s = 0.f;
        for (int j = 0; j < 128; ++j) s = fmaf(W_in[k * 128 + j], W1[j * 128 + n], s);
        Bp1[((size_t)(k >> 3) * 128 + n) * 8 + (k & 7)] = f2bf(s);
    } else if (b >= 224 && b < 288) {
        int idx = (b - 224) * 256 + t;
        int k = idx >> 7, n = idx & 127;
        Bp2[((size_t)(k >> 3) * 128 + n) * 8 + (k & 7)] = f2bf(W2[idx]);
    } else if (b == 288) {
        if (t < 128) {
            float s = 0.f;
            for (int k = 0; k < 128; ++k) s = fmaf(b_in[k], W1[k * 128 + t], s);
            cvec[t] = s;
        }
    }
    gridbar(slots, gen, 1);

    // ---- P1: histogram of dst ----
    for (int e = b * 256 + t; e < EE; e += GRID * 256) atomicAdd(&counts[edst[e]], 1);
    gridbar(slots, gen, 2);

    // ---- P2a: per-chunk sums ----
    if (b < NCH) {
        int idx = b * 256 + t;
        int c = (idx < NN) ? counts[idx] : 0;
        #pragma unroll
        for (int d = 32; d; d >>= 1) c += __shfl_down(c, d, 64);
        if (lane == 0) sm.ws[wv] = c;
        __syncthreads();
        if (t == 0) bsum[b] = sm.ws[0] + sm.ws[1] + sm.ws[2] + sm.ws[3];
    }
    gridbar(slots, gen, 3);

    // ---- P2b: scan -> rowptr/cursor/dis ----
    if (b < NCH) {
        sm.sc[t] = (t < NCH) ? bsum[t] : 0;
        __syncthreads();
        #pragma unroll
        for (int d = 1; d < 256; d <<= 1) {
            int v = (t >= d) ? sm.sc[t - d] : 0;
            __syncthreads();
            sm.sc[t] += v;
            __syncthreads();
        }
        int boff = (b == 0) ? 0 : sm.sc[b - 1];
        if (b == 0 && t == 0) rowptr[NN] = sm.sc[NCH - 1];

        int idx = b * 256 + t;
        int c = (idx < NN) ? counts[idx] : 0;
        int v = c;
        #pragma unroll
        for (int d = 1; d < 64; d <<= 1) {
            int u = __shfl_up(v, d, 64);
            if (lane >= d) v += u;
        }
        if (lane == 63) sm.ws[wv] = v;
        __syncthreads();
        int off = boff;
        for (int j = 0; j < wv; ++j) off += sm.ws[j];
        if (idx < NN) {
            int excl = off + v - c;
            rowptr[idx] = excl;
            cursor[idx] = excl;
            dis[idx] = rsqrtf((float)c + 1.0f);
        }
    }
    gridbar(slots, gen, 4);

    // ---- P3: fill CSR with {src, norm} ----
    for (int e = b * 256 + t; e < EE; e += GRID * 256) {
        int s = esrc[e], d = edst[e];
        int pos = atomicAdd(&cursor[d], 1);
        float nrm = dis[s] * dis[d];
        int2 v; v.x = s; v.y = __float_as_int(nrm);
        edata[pos] = v;
    }
    gridbar(slots, gen, 5);

    // ---- P4: mm1 = x @ (W_in W1) ----
    for (int tile = b; tile < NN / 64; tile += GRID) mm_tile<false>(x, Bp1, bufA, tile, wv, lane);
    gridbar(slots, gen, 6);

    // ---- P5: agg1 ----
    for (int grp = b; grp < NN / 4; grp += GRID)
        agg_node(bufA, dis, rowptr, edata, cvec, b1, bufB, grp * 4 + wv, wv, lane, sm.eds);
    gridbar(slots, gen, 7);

    // ---- P6: mm2 = h1 @ W2 ----
    for (int tile = b; tile < NN / 64; tile += GRID) mm_tile<true>(bufB, Bp2, bufA, tile, wv, lane);
    gridbar(slots, gen, 8);

    // ---- P7: agg2 ----
    for (int grp = b; grp < NN / 4; grp += GRID)
        agg_node(bufA, dis, rowptr, edata, nullptr, b2, bufB, grp * 4 + wv, wv, lane, sm.eds);
    gridbar(slots, gen, 9);

    // ---- P8: pool ----
    for (int ch = b; ch < (NN + 511) / 512; ch += GRID) {
        int c2 = lane;
        int n0 = ch * 512 + wv * 128;
        const uint* __restrict__ hv = (const uint*)bufB;
        int cur = -1;
        float a0 = 0.f, a1 = 0.f;
        for (int j = 0; j < 128; ++j) {
            int n = n0 + j;
            if (n >= NN) break;
            int g = batch[n];
            uint u = hv[(size_t)n * 64 + c2];
            if (g != cur) {
                if (cur >= 0) {
                    atomicAdd(&pools[cur * 128 + 2 * c2], a0);
                    atomicAdd(&pools[cur * 128 + 2 * c2 + 1], a1);
                }
                cur = g; a0 = 0.f; a1 = 0.f;
            }
            a0 += bf_lo(u);
            a1 += bf_hi(u);
        }
        if (cur >= 0) {
            atomicAdd(&pools[cur * 128 + 2 * c2], a0);
            atomicAdd(&pools[cur * 128 + 2 * c2 + 1], a1);
        }
    }
    gridbar(slots, gen, 10);

    // ---- P9: final MLP head (block 0) ----
    if (b == 0) {
        if (t < 16) {
            int lo = lower_bound_dev(batch, NN, t);
            int hi = lower_bound_dev(batch, NN, t + 1);
            sm.f.cnt[t] = hi - lo;
        }
        __syncthreads();
        for (int idx = t; idx < 2048; idx += 256) {
            int g = idx >> 7, c = idx & 127;
            float cn = (float)(sm.f.cnt[g] > 1 ? sm.f.cnt[g] : 1);
            sm.f.pooled[g][c] = pools[idx] / cn;
        }
        __syncthreads();
        for (int idx = t; idx < 1024; idx += 256) {
            int g = idx >> 6, j = idx & 63;
            float s = bf1[j];
            for (int k = 0; k < 128; ++k) s = fmaf(sm.f.pooled[g][k], Wf1[k * 64 + j], s);
            sm.f.z[g][j] = fmaxf(s, 0.f);
        }
        __syncthreads();
        if (t < 160) {
            int g = t / 10, k = t % 10;
            float s = bf2[k];
            for (int j = 0; j < 64; ++j) s = fmaf(sm.f.z[g][j], Wf2[j * 10 + k], s);
            out[t] = s;
        }
    }
}

// ---------------- launch ----------------

extern "C" void kernel_launch(void* const* d_in, const int* in_sizes, int n_in,
                              void* d_out, int out_size, void* d_ws, size_t ws_size,
                              hipStream_t stream) {
    const float* x    = (const float*)d_in[0];
    const int* edge   = (const int*)d_in[1];   // [2,E]: src then dst
    const int* batch  = (const int*)d_in[2];
    const float* W_in = (const float*)d_in[3];
    const float* b_in = (const float*)d_in[4];
    const float* W1   = (const float*)d_in[5];
    const float* b1   = (const float*)d_in[6];
    const float* W2   = (const float*)d_in[7];
    const float* b2   = (const float*)d_in[8];
    const float* Wf1  = (const float*)d_in[9];
    const float* bf1  = (const float*)d_in[10];
    const float* Wf2  = (const float*)d_in[11];
    const float* bf2  = (const float*)d_in[12];
    float* out = (float*)d_out;

    char* ws = (char*)d_ws;
    size_t off = 0;
    auto alloc = [&](size_t bytes) -> void* {
        void* p = ws + off;
        off += (bytes + 511) & ~(size_t)511;
        return p;
    };
    int* ctrl     = (int*)alloc(2048 * 4);               // slots[1024] + gen
    int* slots    = ctrl;
    int* gen      = ctrl + 1024;
    int* counts   = (int*)alloc((size_t)NN * 4);
    int* bsum     = (int*)alloc((size_t)NCH * 4);
    int* rowptr   = (int*)alloc((size_t)(NN + 1) * 4);
    int* cursor   = (int*)alloc((size_t)NN * 4);
    float* dis    = (float*)alloc((size_t)NN * 4);
    int2* edata   = (int2*)alloc((size_t)EE * 8);
    float* pools  = (float*)alloc(16 * 128 * 4);
    float* cvec   = (float*)alloc(128 * 4);
    ushort* Bp1   = (ushort*)alloc(128 * 128 * 2);
    ushort* Bp2   = (ushort*)alloc(128 * 128 * 2);
    ushort* bufA  = (ushort*)alloc((size_t)NN * 128 * 2);
    ushort* bufB  = (ushort*)alloc((size_t)NN * 128 * 2);

    // barrier state must start < 1 regardless of ws poison
    hipMemsetAsync(ctrl, 0, 2048 * 4, stream);

    mega<<<GRID, 256, 0, stream>>>(x, edge, edge + EE, batch,
                                   W_in, b_in, W1, b1, W2, b2, Wf1, bf1, Wf2, bf2,
                                   out, slots, gen, counts, bsum, rowptr, cursor,
                                   dis, edata, pools, cvec, Bp1, Bp2, bufA, bufB);
}

// Round 7
// 278.704 us; speedup vs baseline: 13.2060x; 13.2060x over previous
//
#include <hip/hip_runtime.h>

#define NN 40000
#define EE 640000
#define NCH 157   // ceil(NN/256)

typedef unsigned int uint;
typedef unsigned short ushort;
typedef __attribute__((ext_vector_type(8))) short short8;
typedef __attribute__((ext_vector_type(4))) float floatx4;

// ---- bf16 helpers (RNE) ----
__device__ inline ushort f2bf(float f) {
    uint u = __float_as_uint(f);
    return (ushort)((u + 0x7fffu + ((u >> 16) & 1u)) >> 16);
}
__device__ inline float bf_lo(uint u) { return __uint_as_float(u << 16); }
__device__ inline float bf_hi(uint u) { return __uint_as_float(u & 0xffff0000u); }

// ---------------- hist + weight prep (independent work, one launch) ----------------
__global__ __launch_bounds__(256) void histprep_kernel(const int* __restrict__ dst,
                                                       int* __restrict__ counts,
                                                       const float* __restrict__ W_in,
                                                       const float* __restrict__ W1,
                                                       const float* __restrict__ b_in,
                                                       const float* __restrict__ W2,
                                                       ushort* __restrict__ Bp1,
                                                       ushort* __restrict__ Bp2,
                                                       float* __restrict__ cvec) {
    int b = blockIdx.x, t = threadIdx.x;
    if (b < 2500) {
        atomicAdd(&counts[dst[b * 256 + t]], 1);
    } else if (b < 2564) {
        int idx = (b - 2500) * 256 + t;
        int k = idx >> 7, n = idx & 127;
        float s = 0.f;
        for (int j = 0; j < 128; ++j) s = fmaf(W_in[k * 128 + j], W1[j * 128 + n], s);
        Bp1[((size_t)(k >> 3) * 128 + n) * 8 + (k & 7)] = f2bf(s);
    } else if (b < 2628) {
        int idx = (b - 2564) * 256 + t;
        int k = idx >> 7, n = idx & 127;
        Bp2[((size_t)(k >> 3) * 128 + n) * 8 + (k & 7)] = f2bf(W2[idx]);
    } else {
        if (t < 128) {
            float s = 0.f;
            for (int k = 0; k < 128; ++k) s = fmaf(b_in[k], W1[k * 128 + t], s);
            cvec[t] = s;
        }
    }
}

// ---------------- single-pass CSR offsets ----------------
// Each 256-node chunk: local scan + one atomicAdd on goff for its base.
// start[] is NOT globally monotone (capture order random) but segments are
// disjoint and sized by counts[] -> agg uses (start[i], counts[i]).
__global__ __launch_bounds__(256) void scan_kernel(const int* __restrict__ counts,
                                                   int* __restrict__ goff,
                                                   int* __restrict__ start,
                                                   int* __restrict__ cursor,
                                                   float* __restrict__ dis, int N) {
    __shared__ int ws[4];
    __shared__ int sbase;
    int t = threadIdx.x, lane = t & 63, wv = t >> 6;
    int idx = blockIdx.x * 256 + t;
    int c = (idx < N) ? counts[idx] : 0;
    int v = c;
    #pragma unroll
    for (int d = 1; d < 64; d <<= 1) {
        int u = __shfl_up(v, d, 64);
        if (lane >= d) v += u;
    }
    if (lane == 63) ws[wv] = v;
    __syncthreads();
    if (t == 0) {
        int total = ws[0] + ws[1] + ws[2] + ws[3];
        sbase = atomicAdd(goff, total);
    }
    __syncthreads();
    int off = sbase;
    for (int j = 0; j < wv; ++j) off += ws[j];
    if (idx < N) {
        int excl = off + v - c;
        start[idx] = excl;
        cursor[idx] = excl;
        dis[idx] = rsqrtf((float)c + 1.0f);
    }
}

// ---- MFMA 64-row tile: C[64,128](bf16) = A[64,128] @ Bpack ----
template <bool ABF16>
__device__ inline void mm_tile(const void* __restrict__ Av, const ushort* __restrict__ Bpack,
                               ushort* __restrict__ C, int tile, int wv, int lane) {
    int m = lane & 15, q = lane >> 4;
    int row = tile * 64 + wv * 16 + m;

    short8 afr[4];
    if (ABF16) {
        const ushort* A = (const ushort*)Av;
        const ushort* ap = A + (size_t)row * 128 + q * 8;
        #pragma unroll
        for (int k0 = 0; k0 < 4; ++k0) afr[k0] = *(const short8*)(ap + k0 * 32);
    } else {
        const float* A = (const float*)Av;
        const float* ap = A + (size_t)row * 128 + q * 8;
        #pragma unroll
        for (int k0 = 0; k0 < 4; ++k0) {
            float4 f0 = *(const float4*)(ap + k0 * 32);
            float4 f1 = *(const float4*)(ap + k0 * 32 + 4);
            short8 a;
            a[0] = (short)f2bf(f0.x); a[1] = (short)f2bf(f0.y);
            a[2] = (short)f2bf(f0.z); a[3] = (short)f2bf(f0.w);
            a[4] = (short)f2bf(f1.x); a[5] = (short)f2bf(f1.y);
            a[6] = (short)f2bf(f1.z); a[7] = (short)f2bf(f1.w);
            afr[k0] = a;
        }
    }

    floatx4 acc[8];
    #pragma unroll
    for (int nt = 0; nt < 8; ++nt) { floatx4 z = {0.f, 0.f, 0.f, 0.f}; acc[nt] = z; }

    #pragma unroll
    for (int nt = 0; nt < 8; ++nt) {
        #pragma unroll
        for (int k0 = 0; k0 < 4; ++k0) {
            short8 bfrag = *(const short8*)(Bpack + ((size_t)(k0 * 4 + q) * 128 + nt * 16 + m) * 8);
            acc[nt] = __builtin_amdgcn_mfma_f32_16x16x32_bf16(afr[k0], bfrag, acc[nt], 0, 0, 0);
        }
    }

    int orow_base = tile * 64 + wv * 16 + q * 4;
    #pragma unroll
    for (int nt = 0; nt < 8; ++nt) {
        #pragma unroll
        for (int r = 0; r < 4; ++r)
            C[(size_t)(orow_base + r) * 128 + nt * 16 + m] = f2bf(acc[nt][r]);
    }
}

// ---------------- fill CSR ∪ mm1 (independent, one launch) ----------------
__global__ __launch_bounds__(256) void fillmm1_kernel(const int* __restrict__ src,
                                                      const int* __restrict__ dst,
                                                      const float* __restrict__ dis,
                                                      int* __restrict__ cursor,
                                                      int2* __restrict__ edata,
                                                      const float* __restrict__ x,
                                                      const ushort* __restrict__ Bp1,
                                                      ushort* __restrict__ bufA) {
    int b = blockIdx.x, t = threadIdx.x;
    if (b < 2500) {
        int e = b * 256 + t;
        int s = src[e], d = dst[e];
        int pos = atomicAdd(&cursor[d], 1);
        float nrm = dis[s] * dis[d];
        int2 v; v.x = s; v.y = __float_as_int(nrm);
        edata[pos] = v;
    } else {
        mm_tile<false>(x, Bp1, bufA, b - 2500, t >> 6, t & 63);
    }
}

__global__ __launch_bounds__(256) void mm2_kernel(const ushort* __restrict__ A,
                                                  const ushort* __restrict__ Bp2,
                                                  ushort* __restrict__ C) {
    mm_tile<true>(A, Bp2, C, blockIdx.x, threadIdx.x >> 6, threadIdx.x & 63);
}

// ---------------- GCN aggregation: one wave per dst node ----------------
__global__ __launch_bounds__(256) void agg_kernel(const ushort* __restrict__ hw,
                                                  const float* __restrict__ dis,
                                                  const int* __restrict__ start,
                                                  const int* __restrict__ counts,
                                                  const int2* __restrict__ edata,
                                                  const float* __restrict__ cvec,
                                                  const float* __restrict__ bias,
                                                  ushort* __restrict__ out, int N) {
    __shared__ int2 eds[4][64];
    int wv = threadIdx.x >> 6;
    int lane = threadIdx.x & 63;
    int i = blockIdx.x * 4 + wv;
    if (i >= N) return;
    int beg = start[i];
    int deg = counts[i];
    int dmain = deg > 64 ? 64 : deg;
    const uint* __restrict__ hv = (const uint*)hw;

    int2 ed;
    if (lane < dmain) ed = edata[beg + lane];
    else { ed.x = i; ed.y = 0; }
    eds[wv][lane] = ed;

    float di = dis[i];
    float sii = di * di;
    uint su = hv[(size_t)i * 64 + lane];
    float a0 = sii * bf_lo(su);
    float a1 = sii * bf_hi(su);
    float sumnorm = sii;

    int dpad = (dmain + 7) & ~7;
    for (int j = 0; j < dpad; j += 8) {
        int2 e0 = eds[wv][j],     e1 = eds[wv][j + 1];
        int2 e2 = eds[wv][j + 2], e3 = eds[wv][j + 3];
        int2 e4 = eds[wv][j + 4], e5 = eds[wv][j + 5];
        int2 e6 = eds[wv][j + 6], e7 = eds[wv][j + 7];
        uint u0 = hv[(size_t)e0.x * 64 + lane];
        uint u1 = hv[(size_t)e1.x * 64 + lane];
        uint u2 = hv[(size_t)e2.x * 64 + lane];
        uint u3 = hv[(size_t)e3.x * 64 + lane];
        uint u4 = hv[(size_t)e4.x * 64 + lane];
        uint u5 = hv[(size_t)e5.x * 64 + lane];
        uint u6 = hv[(size_t)e6.x * 64 + lane];
        uint u7 = hv[(size_t)e7.x * 64 + lane];
        float n0 = __int_as_float(e0.y), n1 = __int_as_float(e1.y);
        float n2 = __int_as_float(e2.y), n3 = __int_as_float(e3.y);
        float n4 = __int_as_float(e4.y), n5 = __int_as_float(e5.y);
        float n6 = __int_as_float(e6.y), n7 = __int_as_float(e7.y);
        a0 = fmaf(n0, bf_lo(u0), a0); a1 = fmaf(n0, bf_hi(u0), a1);
        a0 = fmaf(n1, bf_lo(u1), a0); a1 = fmaf(n1, bf_hi(u1), a1);
        a0 = fmaf(n2, bf_lo(u2), a0); a1 = fmaf(n2, bf_hi(u2), a1);
        a0 = fmaf(n3, bf_lo(u3), a0); a1 = fmaf(n3, bf_hi(u3), a1);
        a0 = fmaf(n4, bf_lo(u4), a0); a1 = fmaf(n4, bf_hi(u4), a1);
        a0 = fmaf(n5, bf_lo(u5), a0); a1 = fmaf(n5, bf_hi(u5), a1);
        a0 = fmaf(n6, bf_lo(u6), a0); a1 = fmaf(n6, bf_hi(u6), a1);
        a0 = fmaf(n7, bf_lo(u7), a0); a1 = fmaf(n7, bf_hi(u7), a1);
        sumnorm += ((n0 + n1) + (n2 + n3)) + ((n4 + n5) + (n6 + n7));
    }
    for (int e = beg + 64; e < beg + deg; ++e) {   // rare deg>64 tail
        int2 et = edata[e];
        float n0 = __int_as_float(et.y);
        uint u0 = hv[(size_t)et.x * 64 + lane];
        a0 = fmaf(n0, bf_lo(u0), a0);
        a1 = fmaf(n0, bf_hi(u0), a1);
        sumnorm += n0;
    }

    float c0 = 0.f, c1 = 0.f;
    if (cvec) { c0 = cvec[2 * lane]; c1 = cvec[2 * lane + 1]; }
    float b0 = bias[2 * lane], b1 = bias[2 * lane + 1];
    float o0 = fmaxf(fmaf(sumnorm, c0, a0) + b0, 0.f);
    float o1 = fmaxf(fmaf(sumnorm, c1, a1) + b1, 0.f);
    uint o = (uint)f2bf(o0) | ((uint)f2bf(o1) << 16);
    ((uint*)out)[(size_t)i * 64 + lane] = o;
}

// ---------------- pool + final (last-block ticket) ----------------
__device__ inline int lower_bound_dev(const int* __restrict__ a, int n, int x) {
    int lo = 0, hi = n;
    while (lo < hi) { int m = (lo + hi) >> 1; if (a[m] < x) lo = m + 1; else hi = m; }
    return lo;
}

__global__ __launch_bounds__(256) void poolfinal_kernel(const ushort* __restrict__ h,
                                                        const int* __restrict__ batch,
                                                        float* __restrict__ pools,
                                                        int* __restrict__ ticket,
                                                        const float* __restrict__ Wf1,
                                                        const float* __restrict__ bf1,
                                                        const float* __restrict__ Wf2,
                                                        const float* __restrict__ bf2,
                                                        float* __restrict__ out, int N) {
    __shared__ float pooled[16][128];
    __shared__ float z[16][64];
    __shared__ int cnt[16];
    __shared__ int slast;
    int t = threadIdx.x;
    int c2 = t & 63, wv = t >> 6;
    int n0 = blockIdx.x * 512 + wv * 128;
    const uint* __restrict__ hv = (const uint*)h;
    int cur = -1;
    float a0 = 0.f, a1 = 0.f;
    for (int j = 0; j < 128; ++j) {
        int n = n0 + j;
        if (n >= N) break;
        int g = batch[n];
        uint u = hv[(size_t)n * 64 + c2];
        if (g != cur) {
            if (cur >= 0) {
                atomicAdd(&pools[cur * 128 + 2 * c2], a0);
                atomicAdd(&pools[cur * 128 + 2 * c2 + 1], a1);
            }
            cur = g; a0 = 0.f; a1 = 0.f;
        }
        a0 += bf_lo(u);
        a1 += bf_hi(u);
    }
    if (cur >= 0) {
        atomicAdd(&pools[cur * 128 + 2 * c2], a0);
        atomicAdd(&pools[cur * 128 + 2 * c2 + 1], a1);
    }

    // last arriving block runs the MLP head
    __syncthreads();
    __threadfence();
    if (t == 0) slast = atomicAdd(ticket, 1);
    __syncthreads();
    if (slast != (int)gridDim.x - 1) return;

    if (t < 16) {
        int lo = lower_bound_dev(batch, N, t);
        int hi = lower_bound_dev(batch, N, t + 1);
        cnt[t] = hi - lo;
    }
    __syncthreads();
    for (int idx = t; idx < 2048; idx += 256) {
        int g = idx >> 7, c = idx & 127;
        float cn = (float)(cnt[g] > 1 ? cnt[g] : 1);
        float ps = __hip_atomic_load(&pools[idx], __ATOMIC_RELAXED, __HIP_MEMORY_SCOPE_AGENT);
        pooled[g][c] = ps / cn;
    }
    __syncthreads();
    for (int idx = t; idx < 1024; idx += 256) {
        int g = idx >> 6, j = idx & 63;
        float s = bf1[j];
        for (int k = 0; k < 128; ++k) s = fmaf(pooled[g][k], Wf1[k * 64 + j], s);
        z[g][j] = fmaxf(s, 0.f);
    }
    __syncthreads();
    if (t < 160) {
        int g = t / 10, k = t % 10;
        float s = bf2[k];
        for (int j = 0; j < 64; ++j) s = fmaf(z[g][j], Wf2[j * 10 + k], s);
        out[t] = s;
    }
}

// ---------------- launch ----------------

extern "C" void kernel_launch(void* const* d_in, const int* in_sizes, int n_in,
                              void* d_out, int out_size, void* d_ws, size_t ws_size,
                              hipStream_t stream) {
    const float* x    = (const float*)d_in[0];
    const int* edge   = (const int*)d_in[1];   // [2,E]: src then dst
    const int* batch  = (const int*)d_in[2];
    const float* W_in = (const float*)d_in[3];
    const float* b_in = (const float*)d_in[4];
    const float* W1   = (const float*)d_in[5];
    const float* b1   = (const float*)d_in[6];
    const float* W2   = (const float*)d_in[7];
    const float* b2   = (const float*)d_in[8];
    const float* Wf1  = (const float*)d_in[9];
    const float* bf1  = (const float*)d_in[10];
    const float* Wf2  = (const float*)d_in[11];
    const float* bf2  = (const float*)d_in[12];
    float* out = (float*)d_out;

    char* ws = (char*)d_ws;
    size_t off = 0;
    auto alloc = [&](size_t bytes) -> void* {
        void* p = ws + off;
        off += (bytes + 511) & ~(size_t)511;
        return p;
    };
    // zero region: counts + pools + {goff, ticket} -> one memset
    int* counts   = (int*)alloc((size_t)NN * 4);   // 160256 padded
    float* pools  = (float*)alloc(16 * 128 * 4);   // 8192
    int* misc     = (int*)alloc(512);              // goff, ticket
    size_t zero_bytes = off;                        // contiguous from ws start
    int* goff     = misc;
    int* ticket   = misc + 1;
    ushort* bufA  = (ushort*)alloc((size_t)NN * 128 * 2);
    ushort* bufB  = (ushort*)alloc((size_t)NN * 128 * 2);
    ushort* Bp1   = (ushort*)alloc(128 * 128 * 2);
    ushort* Bp2   = (ushort*)alloc(128 * 128 * 2);
    float* cvec   = (float*)alloc(128 * 4);
    float* dis    = (float*)alloc((size_t)NN * 4);
    int* start    = (int*)alloc((size_t)NN * 4);
    int* cursor   = (int*)alloc((size_t)NN * 4);
    int2* edata   = (int2*)alloc((size_t)EE * 8);

    hipMemsetAsync(counts, 0, zero_bytes, stream);

    histprep_kernel<<<2629, 256, 0, stream>>>(edge + EE, counts, W_in, W1, b_in, W2,
                                              Bp1, Bp2, cvec);
    scan_kernel<<<NCH, 256, 0, stream>>>(counts, goff, start, cursor, dis, NN);
    fillmm1_kernel<<<2500 + NN / 64, 256, 0, stream>>>(edge, edge + EE, dis, cursor,
                                                       edata, x, Bp1, bufA);
    agg_kernel<<<NN / 4, 256, 0, stream>>>(bufA, dis, start, counts, edata, cvec, b1, bufB, NN);
    mm2_kernel<<<NN / 64, 256, 0, stream>>>(bufB, Bp2, bufA);
    agg_kernel<<<NN / 4, 256, 0, stream>>>(bufA, dis, start, counts, edata, nullptr, b2, bufB, NN);
    poolfinal_kernel<<<(NN + 511) / 512, 256, 0, stream>>>(bufB, batch, pools, ticket,
                                                           Wf1, bf1, Wf2, bf2, out, NN);
}

// Round 8
// 240.306 us; speedup vs baseline: 15.3161x; 1.1598x over previous
//
#include <hip/hip_runtime.h>

#define NN 40000
#define EE 640000
#define NCH 157   // ceil(NN/256)

typedef unsigned int uint;
typedef unsigned short ushort;
typedef __attribute__((ext_vector_type(8))) short short8;
typedef __attribute__((ext_vector_type(4))) float floatx4;

// ---- bf16 helpers (RNE) ----
__device__ inline ushort f2bf(float f) {
    uint u = __float_as_uint(f);
    return (ushort)((u + 0x7fffu + ((u >> 16) & 1u)) >> 16);
}
__device__ inline float bf_lo(uint u) { return __uint_as_float(u << 16); }
__device__ inline float bf_hi(uint u) { return __uint_as_float(u & 0xffff0000u); }

__device__ inline int lower_bound_dev(const int* __restrict__ a, int n, int x) {
    int lo = 0, hi = n;
    while (lo < hi) { int m = (lo + hi) >> 1; if (a[m] < x) lo = m + 1; else hi = m; }
    return lo;
}

// ---------------- hist + weight prep + graph bounds (one launch) ----------------
__global__ __launch_bounds__(256) void histprep_kernel(const int* __restrict__ dst,
                                                       int* __restrict__ counts,
                                                       const float* __restrict__ W_in,
                                                       const float* __restrict__ W1,
                                                       const float* __restrict__ b_in,
                                                       const float* __restrict__ W2,
                                                       const int* __restrict__ batch,
                                                       ushort* __restrict__ Bp1,
                                                       ushort* __restrict__ Bp2,
                                                       float* __restrict__ cvec,
                                                       int* __restrict__ glo) {
    int b = blockIdx.x, t = threadIdx.x;
    if (b < 2500) {
        atomicAdd(&counts[dst[b * 256 + t]], 1);
    } else if (b < 2564) {
        int idx = (b - 2500) * 256 + t;
        int k = idx >> 7, n = idx & 127;
        float s = 0.f;
        for (int j = 0; j < 128; ++j) s = fmaf(W_in[k * 128 + j], W1[j * 128 + n], s);
        Bp1[((size_t)(k >> 3) * 128 + n) * 8 + (k & 7)] = f2bf(s);
    } else if (b < 2628) {
        int idx = (b - 2564) * 256 + t;
        int k = idx >> 7, n = idx & 127;
        Bp2[((size_t)(k >> 3) * 128 + n) * 8 + (k & 7)] = f2bf(W2[idx]);
    } else {
        if (t < 128) {
            float s = 0.f;
            for (int k = 0; k < 128; ++k) s = fmaf(b_in[k], W1[k * 128 + t], s);
            cvec[t] = s;
        } else if (t < 128 + 17) {
            int g = t - 128;                      // 0..16
            glo[g] = lower_bound_dev(batch, NN, g);
        }
    }
}

// ---------------- single-pass CSR offsets ----------------
__global__ __launch_bounds__(256) void scan_kernel(const int* __restrict__ counts,
                                                   int* __restrict__ goff,
                                                   int* __restrict__ start,
                                                   int* __restrict__ cursor,
                                                   float* __restrict__ dis, int N) {
    __shared__ int ws[4];
    __shared__ int sbase;
    int t = threadIdx.x, lane = t & 63, wv = t >> 6;
    int idx = blockIdx.x * 256 + t;
    int c = (idx < N) ? counts[idx] : 0;
    int v = c;
    #pragma unroll
    for (int d = 1; d < 64; d <<= 1) {
        int u = __shfl_up(v, d, 64);
        if (lane >= d) v += u;
    }
    if (lane == 63) ws[wv] = v;
    __syncthreads();
    if (t == 0) {
        int total = ws[0] + ws[1] + ws[2] + ws[3];
        sbase = atomicAdd(goff, total);
    }
    __syncthreads();
    int off = sbase;
    for (int j = 0; j < wv; ++j) off += ws[j];
    if (idx < N) {
        int excl = off + v - c;
        start[idx] = excl;
        cursor[idx] = excl;
        dis[idx] = rsqrtf((float)c + 1.0f);
    }
}

// ---- MFMA 64-row tile: C[64,128](bf16) = A[64,128] @ Bpack ----
template <bool ABF16>
__device__ inline void mm_tile(const void* __restrict__ Av, const ushort* __restrict__ Bpack,
                               ushort* __restrict__ C, int tile, int wv, int lane) {
    int m = lane & 15, q = lane >> 4;
    int row = tile * 64 + wv * 16 + m;

    short8 afr[4];
    if (ABF16) {
        const ushort* A = (const ushort*)Av;
        const ushort* ap = A + (size_t)row * 128 + q * 8;
        #pragma unroll
        for (int k0 = 0; k0 < 4; ++k0) afr[k0] = *(const short8*)(ap + k0 * 32);
    } else {
        const float* A = (const float*)Av;
        const float* ap = A + (size_t)row * 128 + q * 8;
        #pragma unroll
        for (int k0 = 0; k0 < 4; ++k0) {
            float4 f0 = *(const float4*)(ap + k0 * 32);
            float4 f1 = *(const float4*)(ap + k0 * 32 + 4);
            short8 a;
            a[0] = (short)f2bf(f0.x); a[1] = (short)f2bf(f0.y);
            a[2] = (short)f2bf(f0.z); a[3] = (short)f2bf(f0.w);
            a[4] = (short)f2bf(f1.x); a[5] = (short)f2bf(f1.y);
            a[6] = (short)f2bf(f1.z); a[7] = (short)f2bf(f1.w);
            afr[k0] = a;
        }
    }

    floatx4 acc[8];
    #pragma unroll
    for (int nt = 0; nt < 8; ++nt) { floatx4 z = {0.f, 0.f, 0.f, 0.f}; acc[nt] = z; }

    #pragma unroll
    for (int nt = 0; nt < 8; ++nt) {
        #pragma unroll
        for (int k0 = 0; k0 < 4; ++k0) {
            short8 bfrag = *(const short8*)(Bpack + ((size_t)(k0 * 4 + q) * 128 + nt * 16 + m) * 8);
            acc[nt] = __builtin_amdgcn_mfma_f32_16x16x32_bf16(afr[k0], bfrag, acc[nt], 0, 0, 0);
        }
    }

    int orow_base = tile * 64 + wv * 16 + q * 4;
    #pragma unroll
    for (int nt = 0; nt < 8; ++nt) {
        #pragma unroll
        for (int r = 0; r < 4; ++r)
            C[(size_t)(orow_base + r) * 128 + nt * 16 + m] = f2bf(acc[nt][r]);
    }
}

// ---------------- fill CSR ∪ mm1 (independent, one launch) ----------------
__global__ __launch_bounds__(256) void fillmm1_kernel(const int* __restrict__ src,
                                                      const int* __restrict__ dst,
                                                      const float* __restrict__ dis,
                                                      int* __restrict__ cursor,
                                                      int2* __restrict__ edata,
                                                      const float* __restrict__ x,
                                                      const ushort* __restrict__ Bp1,
                                                      ushort* __restrict__ bufA) {
    int b = blockIdx.x, t = threadIdx.x;
    if (b < 2500) {
        int e = b * 256 + t;
        int s = src[e], d = dst[e];
        int pos = atomicAdd(&cursor[d], 1);
        float nrm = dis[s] * dis[d];
        int2 v; v.x = s; v.y = __float_as_int(nrm);
        edata[pos] = v;
    } else {
        mm_tile<false>(x, Bp1, bufA, b - 2500, t >> 6, t & 63);
    }
}

__global__ __launch_bounds__(256) void mm2_kernel(const ushort* __restrict__ A,
                                                  const ushort* __restrict__ Bp2,
                                                  ushort* __restrict__ C) {
    mm_tile<true>(A, Bp2, C, blockIdx.x, threadIdx.x >> 6, threadIdx.x & 63);
}

// ---------------- GCN aggregation: one wave per dst node ----------------
__global__ __launch_bounds__(256) void agg_kernel(const ushort* __restrict__ hw,
                                                  const float* __restrict__ dis,
                                                  const int* __restrict__ start,
                                                  const int* __restrict__ counts,
                                                  const int2* __restrict__ edata,
                                                  const float* __restrict__ cvec,
                                                  const float* __restrict__ bias,
                                                  ushort* __restrict__ out, int N) {
    __shared__ int2 eds[4][64];
    int wv = threadIdx.x >> 6;
    int lane = threadIdx.x & 63;
    int i = blockIdx.x * 4 + wv;
    if (i >= N) return;
    int beg = start[i];
    int deg = counts[i];
    int dmain = deg > 64 ? 64 : deg;
    const uint* __restrict__ hv = (const uint*)hw;

    int2 ed;
    if (lane < dmain) ed = edata[beg + lane];
    else { ed.x = i; ed.y = 0; }
    eds[wv][lane] = ed;

    float di = dis[i];
    float sii = di * di;
    uint su = hv[(size_t)i * 64 + lane];
    float a0 = sii * bf_lo(su);
    float a1 = sii * bf_hi(su);
    float sumnorm = sii;

    int dpad = (dmain + 7) & ~7;
    for (int j = 0; j < dpad; j += 8) {
        int2 e0 = eds[wv][j],     e1 = eds[wv][j + 1];
        int2 e2 = eds[wv][j + 2], e3 = eds[wv][j + 3];
        int2 e4 = eds[wv][j + 4], e5 = eds[wv][j + 5];
        int2 e6 = eds[wv][j + 6], e7 = eds[wv][j + 7];
        uint u0 = hv[(size_t)e0.x * 64 + lane];
        uint u1 = hv[(size_t)e1.x * 64 + lane];
        uint u2 = hv[(size_t)e2.x * 64 + lane];
        uint u3 = hv[(size_t)e3.x * 64 + lane];
        uint u4 = hv[(size_t)e4.x * 64 + lane];
        uint u5 = hv[(size_t)e5.x * 64 + lane];
        uint u6 = hv[(size_t)e6.x * 64 + lane];
        uint u7 = hv[(size_t)e7.x * 64 + lane];
        float n0 = __int_as_float(e0.y), n1 = __int_as_float(e1.y);
        float n2 = __int_as_float(e2.y), n3 = __int_as_float(e3.y);
        float n4 = __int_as_float(e4.y), n5 = __int_as_float(e5.y);
        float n6 = __int_as_float(e6.y), n7 = __int_as_float(e7.y);
        a0 = fmaf(n0, bf_lo(u0), a0); a1 = fmaf(n0, bf_hi(u0), a1);
        a0 = fmaf(n1, bf_lo(u1), a0); a1 = fmaf(n1, bf_hi(u1), a1);
        a0 = fmaf(n2, bf_lo(u2), a0); a1 = fmaf(n2, bf_hi(u2), a1);
        a0 = fmaf(n3, bf_lo(u3), a0); a1 = fmaf(n3, bf_hi(u3), a1);
        a0 = fmaf(n4, bf_lo(u4), a0); a1 = fmaf(n4, bf_hi(u4), a1);
        a0 = fmaf(n5, bf_lo(u5), a0); a1 = fmaf(n5, bf_hi(u5), a1);
        a0 = fmaf(n6, bf_lo(u6), a0); a1 = fmaf(n6, bf_hi(u6), a1);
        a0 = fmaf(n7, bf_lo(u7), a0); a1 = fmaf(n7, bf_hi(u7), a1);
        sumnorm += ((n0 + n1) + (n2 + n3)) + ((n4 + n5) + (n6 + n7));
    }
    for (int e = beg + 64; e < beg + deg; ++e) {   // rare deg>64 tail
        int2 et = edata[e];
        float n0 = __int_as_float(et.y);
        uint u0 = hv[(size_t)et.x * 64 + lane];
        a0 = fmaf(n0, bf_lo(u0), a0);
        a1 = fmaf(n0, bf_hi(u0), a1);
        sumnorm += n0;
    }

    float c0 = 0.f, c1 = 0.f;
    if (cvec) { c0 = cvec[2 * lane]; c1 = cvec[2 * lane + 1]; }
    float b0 = bias[2 * lane], b1 = bias[2 * lane + 1];
    float o0 = fmaxf(fmaf(sumnorm, c0, a0) + b0, 0.f);
    float o1 = fmaxf(fmaf(sumnorm, c1, a1) + b1, 0.f);
    uint o = (uint)f2bf(o0) | ((uint)f2bf(o1) << 16);
    ((uint*)out)[(size_t)i * 64 + lane] = o;
}

// ---------------- pool + final: branch-free per-(graph,chunk) blocks ----------------
// 128 blocks: g = b>>3, ch = b&7. Wave sums strided rows of graph g, one
// atomicAdd pair per lane. Last-arriving block runs the MLP head.
__global__ __launch_bounds__(256) void poolfinal_kernel(const ushort* __restrict__ h,
                                                        const int* __restrict__ glo,
                                                        float* __restrict__ pools,
                                                        int* __restrict__ ticket,
                                                        const float* __restrict__ Wf1,
                                                        const float* __restrict__ bf1,
                                                        const float* __restrict__ Wf2,
                                                        const float* __restrict__ bf2,
                                                        float* __restrict__ out) {
    __shared__ float pooled[16][128];
    __shared__ float z[16][64];
    __shared__ int slast;
    int t = threadIdx.x, c2 = t & 63, wv = t >> 6;
    int b = blockIdx.x;
    int g = b >> 3, ch = b & 7;
    int lo = glo[g], hi = glo[g + 1];
    int span = hi - lo;
    int chunk = (span + 7) >> 3;
    int r0 = lo + ch * chunk;
    int r1 = hi < r0 + chunk ? hi : r0 + chunk;
    const uint* __restrict__ hv = (const uint*)h;

    float a0 = 0.f, a1 = 0.f;
    #pragma unroll 4
    for (int j = r0 + wv; j < r1; j += 4) {
        uint u = hv[(size_t)j * 64 + c2];
        a0 += bf_lo(u);
        a1 += bf_hi(u);
    }
    if (r0 < r1) {
        atomicAdd(&pools[g * 128 + 2 * c2], a0);
        atomicAdd(&pools[g * 128 + 2 * c2 + 1], a1);
    }

    __syncthreads();
    __threadfence();
    if (t == 0) slast = atomicAdd(ticket, 1);
    __syncthreads();
    if (slast != 127) return;

    // final MLP head
    for (int idx = t; idx < 2048; idx += 256) {
        int gg = idx >> 7, c = idx & 127;
        int cn = glo[gg + 1] - glo[gg];
        float cnf = (float)(cn > 1 ? cn : 1);
        float ps = __hip_atomic_load(&pools[idx], __ATOMIC_RELAXED, __HIP_MEMORY_SCOPE_AGENT);
        pooled[gg][c] = ps / cnf;
    }
    __syncthreads();
    for (int idx = t; idx < 1024; idx += 256) {
        int gg = idx >> 6, j = idx & 63;
        float s = bf1[j];
        for (int k = 0; k < 128; ++k) s = fmaf(pooled[gg][k], Wf1[k * 64 + j], s);
        z[gg][j] = fmaxf(s, 0.f);
    }
    __syncthreads();
    if (t < 160) {
        int gg = t / 10, k = t % 10;
        float s = bf2[k];
        for (int j = 0; j < 64; ++j) s = fmaf(z[gg][j], Wf2[j * 10 + k], s);
        out[t] = s;
    }
}

// ---------------- launch ----------------

extern "C" void kernel_launch(void* const* d_in, const int* in_sizes, int n_in,
                              void* d_out, int out_size, void* d_ws, size_t ws_size,
                              hipStream_t stream) {
    const float* x    = (const float*)d_in[0];
    const int* edge   = (const int*)d_in[1];   // [2,E]: src then dst
    const int* batch  = (const int*)d_in[2];
    const float* W_in = (const float*)d_in[3];
    const float* b_in = (const float*)d_in[4];
    const float* W1   = (const float*)d_in[5];
    const float* b1   = (const float*)d_in[6];
    const float* W2   = (const float*)d_in[7];
    const float* b2   = (const float*)d_in[8];
    const float* Wf1  = (const float*)d_in[9];
    const float* bf1  = (const float*)d_in[10];
    const float* Wf2  = (const float*)d_in[11];
    const float* bf2  = (const float*)d_in[12];
    float* out = (float*)d_out;

    char* ws = (char*)d_ws;
    size_t off = 0;
    auto alloc = [&](size_t bytes) -> void* {
        void* p = ws + off;
        off += (bytes + 511) & ~(size_t)511;
        return p;
    };
    // zero region: counts + pools + {goff, ticket, glo[17]} -> one memset
    int* counts   = (int*)alloc((size_t)NN * 4);
    float* pools  = (float*)alloc(16 * 128 * 4);
    int* misc     = (int*)alloc(512);
    size_t zero_bytes = off;
    int* goff     = misc;
    int* ticket   = misc + 1;
    int* glo      = misc + 8;                      // 17 ints
    ushort* bufA  = (ushort*)alloc((size_t)NN * 128 * 2);
    ushort* bufB  = (ushort*)alloc((size_t)NN * 128 * 2);
    ushort* Bp1   = (ushort*)alloc(128 * 128 * 2);
    ushort* Bp2   = (ushort*)alloc(128 * 128 * 2);
    float* cvec   = (float*)alloc(128 * 4);
    float* dis    = (float*)alloc((size_t)NN * 4);
    int* start    = (int*)alloc((size_t)NN * 4);
    int* cursor   = (int*)alloc((size_t)NN * 4);
    int2* edata   = (int2*)alloc((size_t)EE * 8);

    hipMemsetAsync(counts, 0, zero_bytes, stream);

    histprep_kernel<<<2629, 256, 0, stream>>>(edge + EE, counts, W_in, W1, b_in, W2,
                                              batch, Bp1, Bp2, cvec, glo);
    scan_kernel<<<NCH, 256, 0, stream>>>(counts, goff, start, cursor, dis, NN);
    fillmm1_kernel<<<2500 + NN / 64, 256, 0, stream>>>(edge, edge + EE, dis, cursor,
                                                       edata, x, Bp1, bufA);
    agg_kernel<<<NN / 4, 256, 0, stream>>>(bufA, dis, start, counts, edata, cvec, b1, bufB, NN);
    mm2_kernel<<<NN / 64, 256, 0, stream>>>(bufB, Bp2, bufA);
    agg_kernel<<<NN / 4, 256, 0, stream>>>(bufA, dis, start, counts, edata, nullptr, b2, bufB, NN);
    poolfinal_kernel<<<128, 256, 0, stream>>>(bufB, glo, pools, ticket,
                                              Wf1, bf1, Wf2, bf2, out);
}